// Round 8
// baseline (223.442 us; speedup 1.0000x reference)
//
#include <hip/hip_runtime.h>
#include <math.h>

// B=32, S=4096, D=256  (fp32). MAX_LEN=5000.
// out[b,s,d] = nodes[b,s,d] + (s <= num_nodes[b] ? pe[(s-num_nodes[b]) mod 5000, d] : 0)
// pe[p, 2k] = sin(p * div[k]), pe[p, 2k+1] = cos(p * div[k]), div[k] = exp2(-log2(1e4)*2k/256)
//
// Evidence ledger:
//  - r7 (flat grid, NT load + NT store): ~65 us/dispatch (headline 219.5 - C,
//    C ~= 154 us calibrated over r5-r7), ~4.1 TB/s on 268 MB traffic.
//  - r5/r6 (persistent 2048-block grid, regular load + NT store): 84.5 us,
//    2.38 TB/s, FETCH 64 MB -> persistent structure REGRESSED; abandoned.
//  - Harness fillBufferAligned: 512 MiB @ 6.7 TB/s (84% peak) with REGULAR
//    stores -> local proof the ceiling is reachable on this allocation.
//  - NT-on-both was the previous session's final, never-A/B'd edit. The 1.5x
//    gap (65 vs ~43 us) is unexplained by VALU (4%), branch (uniform), or
//    scalar loads (1/wave). Suspect: NT cache-bits tax the streaming path.
//
// This round, ONE variable: drop both NT hints -> regular load + regular
// store (the 6.29 TB/s copy-ubench configuration). Everything else = r7.
// Predict: 43-52 us if NT was the tax; >70 us reconvicts NT/NT as best.

typedef float v4f __attribute__((ext_vector_type(4)));

__global__ __launch_bounds__(256) void rpe_kernel(const float* __restrict__ nodes,
                                                  const int* __restrict__ num_nodes,
                                                  float* __restrict__ out,
                                                  const int total4) {
    const int tid = blockIdx.x * blockDim.x + threadIdx.x;  // one float4 per thread
    if (tid >= total4) return;                              // never taken at real shape

    const int d4 = tid & 63;           // float4 index within row (64 per row)
    const int s  = (tid >> 6) & 4095;  // sequence position
    const int b  = tid >> 18;          // batch

    const int nn = num_nodes[b];       // wave-uniform (one wave == one row)

    v4f v = reinterpret_cast<const v4f*>(nodes)[tid];   // regular load

    if (s <= nn) {                     // wave-uniform branch
        int r = s - nn;                // r in (-4096, 0]
        int p = (r < 0) ? r + 5000 : r;  // Python mod semantics
        const float pf = (float)p;

        // f[k] = div[k] / (2*pi)  (revolutions per unit position)
        const float cexp   = -0.051905126482062035f;  // -log2(10000)/256
        const float inv2pi = 0.15915494309189535f;
        const float f0 = exp2f(cexp * (float)(4 * d4)) * inv2pi;
        const float f1 = exp2f(cexp * (float)(4 * d4 + 2)) * inv2pi;

        float r0 = pf * f0;  r0 -= floorf(r0);   // [0,1) revolutions
        float r1 = pf * f1;  r1 -= floorf(r1);

        v.x += __builtin_amdgcn_sinf(r0);   // v_sin_f32: sin(2*pi*r0)
        v.y += __builtin_amdgcn_cosf(r0);
        v.z += __builtin_amdgcn_sinf(r1);
        v.w += __builtin_amdgcn_cosf(r1);
    }

    reinterpret_cast<v4f*>(out)[tid] = v;               // regular store
}

extern "C" void kernel_launch(void* const* d_in, const int* in_sizes, int n_in,
                              void* d_out, int out_size, void* d_ws, size_t ws_size,
                              hipStream_t stream) {
    const float* nodes     = (const float*)d_in[0];
    const int*   num_nodes = (const int*)d_in[1];
    float*       out       = (float*)d_out;

    // total float4 elements: 32*4096*256/4 = 8388608 -> 32768 blocks of 256
    const int total4 = out_size / 4;
    const int block  = 256;
    const int grid   = (total4 + block - 1) / block;

    rpe_kernel<<<grid, block, 0, stream>>>(nodes, num_nodes, out, total4);
}

// Round 9
// 220.569 us; speedup vs baseline: 1.0130x; 1.0130x over previous
//
#include <hip/hip_runtime.h>
#include <math.h>

// B=32, S=4096, D=256  (fp32). MAX_LEN=5000.
// out[b,s,d] = nodes[b,s,d] + (s <= num_nodes[b] ? pe[(s-num_nodes[b]) mod 5000, d] : 0)
// pe[p, 2k] = sin(p * div[k]), pe[p, 2k+1] = cos(p * div[k]), div[k] = exp2(-log2(1e4)*2k/256)
//
// Evidence ledger (dispatch times; headline = dispatch + ~157 us of harness
// poison-fills, calibrated r5-r8):
//  - r7 flat 32768 blocks, 1 float4/thread, NT/NT:       ~65 us (4.1 TB/s)
//  - r8 same, regular/regular:                           ~69 us -> policy ~neutral
//  - r5/r6 persistent 2048-block, 8MB-stride batch:       85 us -> abandoned
//  - roofline: 268 MB mixed stream @ 6.3 TB/s ceiling ->  ~43 us
// Diagnosis: 32768 blocks / 65 us = 504 blocks/us = CP dispatch ceiling;
// occupancy measured 54% with nothing static capping it -> CU starvation.
// 17 waves/CU x 1 KB MLP=1 in flight = 17 KB < ~22 KB latency-BW product.
//
// This round: block-contiguous x4 unroll. 8192 blocks; thread t of block blk
// handles float4 indices base+{0,256,512,768} (wave-coalesced, contiguous
// 16 KB per block). Branch-free PE epilogue (cndmask+fmac, no CFG splits ->
// scheduler keeps the 4-load cluster; r6's branchy version got re-serialized
// to VGPR=16). d4 is sweep-invariant -> exp2f pair hoisted (computed once).
// Predict: dispatch 43-55 us, VGPR 28-40, VALUBusy ~8-10%.

typedef float v4f __attribute__((ext_vector_type(4)));

#define BLOCK 256
#define UNROLL 4

__device__ __forceinline__ v4f pe_add(v4f v, int idx, int nn, float f0, float f1) {
    const int s = (idx >> 6) & 4095;       // sequence position (wave-uniform)
    int r = s - nn;                        // no-branch Python mod: r in (-4096, 4096)
    int p = (r < 0) ? r + 5000 : r;        // v_cndmask
    const float pf = (float)p;
    float r0 = pf * f0;  r0 -= floorf(r0); // [0,1) revolutions
    float r1 = pf * f1;  r1 -= floorf(r1);
    const float m = (s <= nn) ? 1.0f : 0.0f;  // v_cndmask mask, no divergence
    v.x = fmaf(m, __builtin_amdgcn_sinf(r0), v.x);  // v_sin_f32: sin(2*pi*r0)
    v.y = fmaf(m, __builtin_amdgcn_cosf(r0), v.y);
    v.z = fmaf(m, __builtin_amdgcn_sinf(r1), v.z);
    v.w = fmaf(m, __builtin_amdgcn_cosf(r1), v.w);
    return v;
}

template <bool EXACT>
__global__ __launch_bounds__(BLOCK) void rpe_kernel(const float* __restrict__ nodes,
                                                    const int* __restrict__ num_nodes,
                                                    float* __restrict__ out,
                                                    const int total4) {
    const int base = blockIdx.x * (BLOCK * UNROLL) + threadIdx.x;

    // d4 identical for all 4 sweeps (sweep stride 256 == 0 mod 64): exp2 once.
    const int d4 = base & 63;
    const float cexp   = -0.051905126482062035f;  // -log2(10000)/256
    const float inv2pi = 0.15915494309189535f;
    const float f0 = exp2f(cexp * (float)(4 * d4)) * inv2pi;
    const float f1 = exp2f(cexp * (float)(4 * d4 + 2)) * inv2pi;

    const v4f* __restrict__ in4  = reinterpret_cast<const v4f*>(nodes);
    v4f* __restrict__       out4 = reinterpret_cast<v4f*>(out);

    if (EXACT) {
        const int i0 = base;
        const int i1 = base + BLOCK;
        const int i2 = base + 2 * BLOCK;
        const int i3 = base + 3 * BLOCK;

        // 4-load cluster (single basic block through to the stores).
        v4f v0 = __builtin_nontemporal_load(in4 + i0);
        v4f v1 = __builtin_nontemporal_load(in4 + i1);
        v4f v2 = __builtin_nontemporal_load(in4 + i2);
        v4f v3 = __builtin_nontemporal_load(in4 + i3);
        // b = idx>>18 wave-uniform; readfirstlane -> one s_load per wave each.
        const int n0 = num_nodes[__builtin_amdgcn_readfirstlane(i0 >> 18)];
        const int n1 = num_nodes[__builtin_amdgcn_readfirstlane(i1 >> 18)];
        const int n2 = num_nodes[__builtin_amdgcn_readfirstlane(i2 >> 18)];
        const int n3 = num_nodes[__builtin_amdgcn_readfirstlane(i3 >> 18)];

        v0 = pe_add(v0, i0, n0, f0, f1);
        v1 = pe_add(v1, i1, n1, f0, f1);
        v2 = pe_add(v2, i2, n2, f0, f1);
        v3 = pe_add(v3, i3, n3, f0, f1);

        __builtin_nontemporal_store(v0, out4 + i0);
        __builtin_nontemporal_store(v1, out4 + i1);
        __builtin_nontemporal_store(v2, out4 + i2);
        __builtin_nontemporal_store(v3, out4 + i3);
    } else {
        #pragma unroll
        for (int j = 0; j < UNROLL; ++j) {
            const int idx = base + j * BLOCK;
            if (idx < total4) {
                v4f v = __builtin_nontemporal_load(in4 + idx);
                const int nn = num_nodes[__builtin_amdgcn_readfirstlane(idx >> 18)];
                v = pe_add(v, idx, nn, f0, f1);
                __builtin_nontemporal_store(v, out4 + idx);
            }
        }
    }
}

extern "C" void kernel_launch(void* const* d_in, const int* in_sizes, int n_in,
                              void* d_out, int out_size, void* d_ws, size_t ws_size,
                              hipStream_t stream) {
    const float* nodes     = (const float*)d_in[0];
    const int*   num_nodes = (const int*)d_in[1];
    float*       out       = (float*)d_out;

    // total float4 elements: 32*4096*256/4 = 8388608 = 8192 * (256*4) exactly
    const int total4 = out_size / 4;
    const int grid   = (total4 + BLOCK * UNROLL - 1) / (BLOCK * UNROLL);

    if (total4 % (BLOCK * UNROLL) == 0) {
        rpe_kernel<true><<<grid, BLOCK, 0, stream>>>(nodes, num_nodes, out, total4);
    } else {
        rpe_kernel<false><<<grid, BLOCK, 0, stream>>>(nodes, num_nodes, out, total4);
    }
}